// Round 1
// baseline (1809.641 us; speedup 1.0000x reference)
//
#include <hip/hip_runtime.h>
#include <hip/hip_bf16.h>
#include <cstdint>
#include <cstddef>

#define B_   8
#define S_   2048
#define H_   2048
#define M_   256
#define E_   8
#define HH_  1024
#define BS_  (B_*S_)   // 16384

typedef _Float16 f16;
typedef _Float16 f16x8 __attribute__((ext_vector_type(8)));
typedef float    f32x4 __attribute__((ext_vector_type(4)));

// ---------------------------------------------------------------- helpers

__device__ __forceinline__ void load16_lds(const void* g, void* l) {
  __builtin_amdgcn_global_load_lds(
      (const __attribute__((address_space(1))) uint32_t*)g,
      (__attribute__((address_space(3))) uint32_t*)l,
      16, 0, 0);
}

__device__ __forceinline__ float fast_tanh(float x) {
  x = fminf(fmaxf(x, -15.f), 15.f);
  float t = __expf(2.f * x);
  return (t - 1.f) / (t + 1.f);
}

// ------------------------------------------- x -> fp16 + pooled partials

// grid (H_/256, S_/64, B_), block 256
__global__ void convert_x_pool(const float* __restrict__ x, f16* __restrict__ xf,
                               float* __restrict__ partial) {
  int h  = blockIdx.x * 256 + threadIdx.x;
  int sc = blockIdx.y;            // 0..31 (64 s each)
  int b  = blockIdx.z;
  size_t base = ((size_t)b * S_ + sc * 64) * H_ + h;
  float sum = 0.f;
  #pragma unroll 4
  for (int i = 0; i < 64; ++i) {
    float v = x[base + (size_t)i * H_];
    sum += v;
    xf[base + (size_t)i * H_] = (f16)v;
  }
  partial[((size_t)b * H_ + h) * 32 + sc] = sum;
}

// grid (B_*H_/256), block 256
__global__ void pool_finalize(const float* __restrict__ partial, float* __restrict__ pooled) {
  int i = blockIdx.x * 256 + threadIdx.x;   // b*H + h
  float s = 0.f;
  #pragma unroll
  for (int c = 0; c < 32; ++c) s += partial[(size_t)i * 32 + c];
  pooled[i] = s * (1.0f / S_);
}

// ----------------------------------------------------------- router (f32)

// grid (B_), block 256 (= M_)
__global__ void router_kernel(const float* __restrict__ pooled,
                              const float* __restrict__ Wm1, const float* __restrict__ bm1,
                              const float* __restrict__ Wm2, const float* __restrict__ bm2,
                              const float* __restrict__ Wm3, const float* __restrict__ bm3,
                              const float* __restrict__ eff, float* __restrict__ wout) {
  __shared__ float pl[H_];
  __shared__ float h1[M_];
  __shared__ float h2[M_];
  __shared__ float lg[E_];
  int b = blockIdx.x;
  int t = threadIdx.x;

  for (int i = t; i < H_; i += 256) pl[i] = pooled[b * H_ + i];
  __syncthreads();

  float s = bm1[t];
  for (int k = 0; k < H_; ++k) s += pl[k] * Wm1[(size_t)k * M_ + t];
  h1[t] = fmaxf(s, 0.f);
  __syncthreads();

  s = bm2[t];
  for (int k = 0; k < M_; ++k) s += h1[k] * Wm2[k * M_ + t];
  h2[t] = fmaxf(s, 0.f);
  __syncthreads();

  if (t < E_) {
    float l = bm3[t];
    for (int k = 0; k < M_; ++k) l += h2[k] * Wm3[k * E_ + t];
    lg[t] = l;
  }
  __syncthreads();

  if (t == 0) {
    float p[E_], q[E_];
    float mx = -1e30f;
    for (int e = 0; e < E_; ++e) mx = fmaxf(mx, lg[e]);
    float den = 0.f;
    for (int e = 0; e < E_; ++e) { p[e] = __expf(lg[e] - mx); den += p[e]; }
    float inv = 1.f / den;
    for (int e = 0; e < E_; ++e) q[e] = p[e] * inv * eff[e];
    mx = -1e30f;
    for (int e = 0; e < E_; ++e) mx = fmaxf(mx, q[e]);
    den = 0.f;
    for (int e = 0; e < E_; ++e) { q[e] = __expf(q[e] - mx); den += q[e]; }
    inv = 1.f / den;
    for (int e = 0; e < E_; ++e) wout[b * E_ + e] = q[e] * inv;
  }
}

// ------------------------------------- weight transpose + f32->f16 convert

// in: [E][R][C] f32  ->  out: [E][C][R] f16.  grid (C/32, R/32, E), block 256
__global__ void transpose_cvt(const float* __restrict__ in, f16* __restrict__ out,
                              int R, int C) {
  __shared__ f16 tile[32][33];
  int e  = blockIdx.z;
  int c0 = blockIdx.x * 32, r0 = blockIdx.y * 32;
  int tx = threadIdx.x & 31, ty = threadIdx.x >> 5;   // 32 x 8
  const float* inp = in + (size_t)e * R * C;
  f16* outp = out + (size_t)e * R * C;
  #pragma unroll
  for (int i = 0; i < 4; ++i) {
    int r = r0 + ty + i * 8;
    tile[ty + i * 8][tx] = (f16)inp[(size_t)r * C + c0 + tx];
  }
  __syncthreads();
  #pragma unroll
  for (int i = 0; i < 4; ++i) {
    int c = c0 + ty + i * 8;
    outp[(size_t)c * R + r0 + tx] = tile[tx][ty + i * 8];
  }
}

// ------------------------------------------------ shared 128x128 K-loop

// A: [*][K] row-major (tile row 0 at A), Bt: [*][K] row-major. Tiles 128x128, BK=32.
__device__ __forceinline__ void gemm_kloop(const f16* __restrict__ A,
                                           const f16* __restrict__ Bt,
                                           int K, f16* As, f16* Bs,
                                           f32x4 acc[4][4]) {
  int t = threadIdx.x, lane = t & 63, w = t >> 6;
  int wr = w >> 1, wc = w & 1;
  int off0 = w * 1024 + lane * 16;                    // bytes in 8KB tile
  int rbase = (wr * 64 + (lane & 15)) * 32 + (lane >> 4) * 8;
  int cbase = (wc * 64 + (lane & 15)) * 32 + (lane >> 4) * 8;

  for (int kt = 0; kt < K; kt += 32) {
    #pragma unroll
    for (int i = 0; i < 2; ++i) {
      int off = off0 + i * 4096;
      int row = off >> 6, kb = off & 63;
      load16_lds((const char*)A  + (size_t)row * (K * 2) + kt * 2 + kb, (char*)As + off);
      load16_lds((const char*)Bt + (size_t)row * (K * 2) + kt * 2 + kb, (char*)Bs + off);
    }
    __syncthreads();
    f16x8 af[4], bf[4];
    #pragma unroll
    for (int m = 0; m < 4; ++m) af[m] = *(const f16x8*)(As + rbase + m * 512);
    #pragma unroll
    for (int n = 0; n < 4; ++n) bf[n] = *(const f16x8*)(Bs + cbase + n * 512);
    #pragma unroll
    for (int m = 0; m < 4; ++m)
      #pragma unroll
      for (int n = 0; n < 4; ++n)
        acc[m][n] = __builtin_amdgcn_mfma_f32_16x16x32_f16(af[m], bf[n], acc[m][n], 0, 0, 0);
    __syncthreads();
  }
}

// --------------------------------------------- GEMM1: he = relu(x@W1 + b1)

// grid (BS_/128, HH_/128, nE), block 256
__global__ __launch_bounds__(256, 2)
void gemm1_kernel(const f16* __restrict__ xf, const f16* __restrict__ W1t,
                  const float* __restrict__ b1, f16* __restrict__ he, int eoff) {
  __shared__ f16 As[128 * 32];
  __shared__ f16 Bs[128 * 32];
  int ew = eoff + blockIdx.z;           // weight/bias expert
  int eh = blockIdx.z;                  // he buffer slot
  int brow = blockIdx.x * 128;
  int bcol = blockIdx.y * 128;
  const f16* A  = xf  + (size_t)brow * H_;
  const f16* Bt = W1t + ((size_t)ew * HH_ + bcol) * H_;

  f32x4 acc[4][4] = {};
  gemm_kloop(A, Bt, H_, As, Bs, acc);

  int t = threadIdx.x, lane = t & 63, w = t >> 6;
  int wr = w >> 1, wc = w & 1;
  int col0 = bcol + wc * 64 + (lane & 15);
  int row0 = brow + wr * 64 + (lane >> 4) * 4;
  f16* C = he + (size_t)eh * BS_ * HH_;
  #pragma unroll
  for (int n = 0; n < 4; ++n) {
    int gc = col0 + n * 16;
    float bias = b1[ew * HH_ + gc];
    #pragma unroll
    for (int m = 0; m < 4; ++m) {
      #pragma unroll
      for (int r = 0; r < 4; ++r) {
        int gr = row0 + m * 16 + r;
        float v = acc[m][n][r] + bias;
        C[(size_t)gr * HH_ + gc] = (f16)fmaxf(v, 0.f);
      }
    }
  }
}

// -------------------- GEMM2 (fused over experts): out = sum_e w*tanh(he@W2+b2)

// grid (BS_/128, H_/128), block 256
__global__ __launch_bounds__(256, 2)
void gemm2_fused(const f16* __restrict__ he, const f16* __restrict__ W2t,
                 const float* __restrict__ b2, const float* __restrict__ wbuf,
                 float* __restrict__ out) {
  __shared__ f16 As[128 * 32];
  __shared__ f16 Bs[128 * 32];
  int brow = blockIdx.x * 128;
  int bcol = blockIdx.y * 128;
  int b = brow >> 11;                   // 2048 rows per batch
  int t = threadIdx.x, lane = t & 63, w = t >> 6;
  int wr = w >> 1, wc = w & 1;
  int col0 = bcol + wc * 64 + (lane & 15);
  int row0 = brow + wr * 64 + (lane >> 4) * 4;

  float tot[4][4][4] = {};

  for (int e = 0; e < E_; ++e) {
    const f16* A  = he  + ((size_t)e * BS_ + brow) * HH_;
    const f16* Bt = W2t + ((size_t)e * H_  + bcol) * HH_;
    float we = wbuf[b * E_ + e];
    f32x4 acc[4][4] = {};
    gemm_kloop(A, Bt, HH_, As, Bs, acc);
    #pragma unroll
    for (int n = 0; n < 4; ++n) {
      float bias = b2[e * H_ + col0 + n * 16];
      #pragma unroll
      for (int m = 0; m < 4; ++m) {
        #pragma unroll
        for (int r = 0; r < 4; ++r)
          tot[m][n][r] += we * fast_tanh(acc[m][n][r] + bias);
      }
    }
    __syncthreads();   // make sure all waves done with LDS before next expert reuse
  }

  #pragma unroll
  for (int n = 0; n < 4; ++n) {
    int gc = col0 + n * 16;
    #pragma unroll
    for (int m = 0; m < 4; ++m) {
      #pragma unroll
      for (int r = 0; r < 4; ++r) {
        int gr = row0 + m * 16 + r;
        out[(size_t)gr * H_ + gc] = tot[m][n][r];
      }
    }
  }
}

// -------------------- GEMM2 fallback: one expert, accumulate into out (f32 RMW)

// grid (BS_/128, H_/128), block 256
__global__ __launch_bounds__(256, 2)
void gemm2_single(const f16* __restrict__ heE, const f16* __restrict__ W2t,
                  const float* __restrict__ b2, const float* __restrict__ wbuf,
                  float* __restrict__ out, int e, int first) {
  __shared__ f16 As[128 * 32];
  __shared__ f16 Bs[128 * 32];
  int brow = blockIdx.x * 128;
  int bcol = blockIdx.y * 128;
  int b = brow >> 11;
  const f16* A  = heE + (size_t)brow * HH_;
  const f16* Bt = W2t + ((size_t)e * H_ + bcol) * HH_;
  float we = wbuf[b * E_ + e];

  f32x4 acc[4][4] = {};
  gemm_kloop(A, Bt, HH_, As, Bs, acc);

  int t = threadIdx.x, lane = t & 63, w = t >> 6;
  int wr = w >> 1, wc = w & 1;
  int col0 = bcol + wc * 64 + (lane & 15);
  int row0 = brow + wr * 64 + (lane >> 4) * 4;
  #pragma unroll
  for (int n = 0; n < 4; ++n) {
    int gc = col0 + n * 16;
    float bias = b2[e * H_ + gc];
    #pragma unroll
    for (int m = 0; m < 4; ++m) {
      #pragma unroll
      for (int r = 0; r < 4; ++r) {
        int gr = row0 + m * 16 + r;
        size_t idx = (size_t)gr * H_ + gc;
        float v = we * fast_tanh(acc[m][n][r] + bias);
        out[idx] = first ? v : (out[idx] + v);
      }
    }
  }
}

// ---------------------------------------------------------------- launch

extern "C" void kernel_launch(void* const* d_in, const int* in_sizes, int n_in,
                              void* d_out, int out_size, void* d_ws, size_t ws_size,
                              hipStream_t stream) {
  const float* x   = (const float*)d_in[0];
  const float* Wm1 = (const float*)d_in[1];
  const float* bm1 = (const float*)d_in[2];
  const float* Wm2 = (const float*)d_in[3];
  const float* bm2 = (const float*)d_in[4];
  const float* Wm3 = (const float*)d_in[5];
  const float* bm3 = (const float*)d_in[6];
  const float* W1  = (const float*)d_in[7];
  const float* b1  = (const float*)d_in[8];
  const float* W2  = (const float*)d_in[9];
  const float* b2  = (const float*)d_in[10];
  const float* eff = (const float*)d_in[11];
  float* out = (float*)d_out;

  char* ws = (char*)d_ws;
  size_t off = 0;
  auto take = [&](size_t bytes) { void* p = ws + off; off += (bytes + 255) & ~(size_t)255; return p; };

  f16*   xf      = (f16*)  take((size_t)BS_ * H_ * 2);        // 64 MB
  f16*   W1t     = (f16*)  take((size_t)E_ * HH_ * H_ * 2);   // 32 MB
  f16*   W2t     = (f16*)  take((size_t)E_ * H_ * HH_ * 2);   // 32 MB
  float* partial = (float*)take((size_t)B_ * H_ * 32 * 4);    // 2 MB
  float* pooled  = (float*)take((size_t)B_ * H_ * 4);
  float* wbuf    = (float*)take(1024);
  size_t he_full = (size_t)E_ * BS_ * HH_ * 2;                // 256 MB
  bool full_path = (off + he_full) <= ws_size;
  f16* he = (f16*)(ws + off);

  // 1. x -> fp16 + pooled partials
  convert_x_pool<<<dim3(H_ / 256, S_ / 64, B_), 256, 0, stream>>>(x, xf, partial);
  // 2. pooled
  pool_finalize<<<(B_ * H_) / 256, 256, 0, stream>>>(partial, pooled);
  // 3. router -> w[b][e]
  router_kernel<<<B_, 256, 0, stream>>>(pooled, Wm1, bm1, Wm2, bm2, Wm3, bm3, eff, wbuf);
  // 4. weight transposes (K-contiguous fp16)
  transpose_cvt<<<dim3(HH_ / 32, H_ / 32, E_), 256, 0, stream>>>(W1, W1t, H_, HH_);
  transpose_cvt<<<dim3(H_ / 32, HH_ / 32, E_), 256, 0, stream>>>(W2, W2t, HH_, H_);

  if (full_path) {
    gemm1_kernel<<<dim3(BS_ / 128, HH_ / 128, E_), 256, 0, stream>>>(xf, W1t, b1, he, 0);
    gemm2_fused<<<dim3(BS_ / 128, H_ / 128), 256, 0, stream>>>(he, W2t, b2, wbuf, out);
  } else {
    for (int e = 0; e < E_; ++e) {
      gemm1_kernel<<<dim3(BS_ / 128, HH_ / 128, 1), 256, 0, stream>>>(xf, W1t, b1, he, e);
      gemm2_single<<<dim3(BS_ / 128, H_ / 128), 256, 0, stream>>>(he, W2t, b2, wbuf, out, e, e == 0);
    }
  }
}

// Round 2
// 1622.592 us; speedup vs baseline: 1.1153x; 1.1153x over previous
//
#include <hip/hip_runtime.h>
#include <hip/hip_bf16.h>
#include <cstdint>
#include <cstddef>

#define B_   8
#define S_   2048
#define H_   2048
#define M_   256
#define E_   8
#define HH_  1024
#define BS_  (B_*S_)   // 16384

typedef _Float16 f16;
typedef _Float16 f16x8 __attribute__((ext_vector_type(8)));
typedef float    f32x4 __attribute__((ext_vector_type(4)));

// ---- pipelined-GEMM LDS geometry (bytes) ----
// slot = A[2 khalf][256 rows][32 f16] (32KB) + B[2 khalf][128 rows][32 f16] (16KB)
#define SLOT_B   49152
#define A_HALF_B 16384
#define B_OFF    32768
#define B_HALF_B 8192

__device__ __forceinline__ void gl_lds16(const void* g, void* l) {
  __builtin_amdgcn_global_load_lds(
      (const __attribute__((address_space(1))) uint32_t*)g,
      (__attribute__((address_space(3))) uint32_t*)l, 16, 0, 0);
}

// inverse of the LDS swizzle S(o) = o ^ (((o>>6)&7)<<4)   (GF(2)-linear, bijective)
__device__ __forceinline__ int sinv(int P) {
  int b8 = (P >> 8) & 1, b7 = (P >> 7) & 1, b6 = (P >> 6) & 1;
  return P ^ (b8 << 6) ^ (b7 << 5) ^ ((b6 ^ b8) << 4);
}

__device__ __forceinline__ float fast_tanh(float x) {
  x = fminf(fmaxf(x, -15.f), 15.f);
  float t = __expf(2.f * x);
  return (t - 1.f) / (t + 1.f);
}

// --------------------------------------------------------------------------
// Pipelined K-loop core: 256x128 tile, 8 waves (4x2), wave tile 64x64,
// BK=64 in two 32-k halves, 3 LDS slots, counted vmcnt(6), setprio MFMA.
// Tile g computes from slot g%3 while tile g+2 stages into slot (g+2)%3.
// --------------------------------------------------------------------------
template<int NG, int NT_LG, int ASEG_SH, int BSEG_SH, class F>
__device__ __forceinline__ void kloop(const char* aS0, const char* aS1,
    const char* bS0, char* ldsc, int aRd, int bRd, int wv, int ln,
    f32x4 (&acc)[4][4], F fold) {
  constexpr int NT = 1 << NT_LG;

  auto stage = [&](int gs, int ss, int h) {
    int tt = gs & (NT - 1);
    size_t ea = 0, eb = 0;
    if constexpr (ASEG_SH != 0) {
      int e = gs >> NT_LG;
      ea = (size_t)e << ASEG_SH;
      eb = (size_t)e << BSEG_SH;
    }
    int koff = tt * 128 + h * 64;
    char* dA = ldsc + ss * SLOT_B + h * A_HALF_B + wv * 1024 + ln * 16;
    gl_lds16(aS0 + ea + koff, dA);
    gl_lds16(aS1 + ea + koff, dA + 8192);
    char* dB = ldsc + ss * SLOT_B + B_OFF + h * B_HALF_B + wv * 1024 + ln * 16;
    gl_lds16(bS0 + eb + koff, dB);
  };

  // prologue: stage tiles 0,1 into slots 0,1 (12 loads/thread), wait tile0
#pragma unroll
  for (int t = 0; t < 2; ++t) { stage(t, t, 0); stage(t, t, 1); }
  asm volatile("s_waitcnt vmcnt(6)" ::: "memory");
  __builtin_amdgcn_s_barrier();

  int s = 0;
#pragma unroll 1
  for (int g = 0; g < NG; ++g) {
    int ss = s + 2; if (ss >= 3) ss -= 3;
    const char* sbase = ldsc + s * SLOT_B;
    bool do_stage = (g + 2) < NG;
#pragma unroll
    for (int h = 0; h < 2; ++h) {
      f16x8 af[4], bf[4];
      const char* aB = sbase + h * A_HALF_B + aRd;
      const char* bB = sbase + B_OFF + h * B_HALF_B + bRd;
#pragma unroll
      for (int m = 0; m < 4; ++m) af[m] = *(const f16x8*)(aB + m * 1024);
#pragma unroll
      for (int n = 0; n < 4; ++n) bf[n] = *(const f16x8*)(bB + n * 1024);
      if (do_stage) stage(g + 2, ss, h);
      __builtin_amdgcn_sched_barrier(0);
      __builtin_amdgcn_s_barrier();
      asm volatile("s_waitcnt lgkmcnt(0)" ::: "memory");
      __builtin_amdgcn_sched_barrier(0);
      __builtin_amdgcn_s_setprio(1);
#pragma unroll
      for (int m = 0; m < 4; ++m)
#pragma unroll
        for (int n = 0; n < 4; ++n)
          acc[m][n] = __builtin_amdgcn_mfma_f32_16x16x32_f16(af[m], bf[n], acc[m][n], 0, 0, 0);
      __builtin_amdgcn_s_setprio(0);
      __builtin_amdgcn_sched_barrier(0);
      if (h == 1) {
        if ((g & (NT - 1)) == (NT - 1)) fold(g >> NT_LG);
        if (g < NG - 2) { asm volatile("s_waitcnt vmcnt(6)" ::: "memory"); }
        else            { asm volatile("s_waitcnt vmcnt(0)" ::: "memory"); }
        __builtin_amdgcn_sched_barrier(0);
      }
      __builtin_amdgcn_s_barrier();
    }
    ++s; if (s >= 3) s -= 3;
  }
}

// ----------------- GEMM1: he[e] = relu(xf @ W1t[e]^T + b1[e]) --------------
// grid 4096 = (nt 8) x (mt 64) x (e 8), block 512
__global__ __launch_bounds__(512, 2) void gemm1_pipe(
    const f16* __restrict__ xf, const f16* __restrict__ W1t,
    const float* __restrict__ b1, f16* __restrict__ he) {
  __shared__ f16 lds[3 * 24576];
  char* ldsc = (char*)lds;
  int tid = threadIdx.x, wv = tid >> 6, ln = tid & 63, l15 = ln & 15, kq = ln >> 4;
  int wr = wv >> 1, wc = wv & 1;

  int id = blockIdx.x;
  int logical = (id & 7) * 512 + (id >> 3);      // XCD-contiguous chunks
  int nt = logical & 7, mt = (logical >> 3) & 63, e = logical >> 9;
  int brow = mt * 256, bcol = nt * 128;

  int mask = (ln & 7) << 4;
  int aRd = ((wr * 64 + l15) * 64 + kq * 16) ^ mask;
  int bRd = ((wc * 64 + l15) * 64 + kq * 16) ^ mask;

  int PA0 = wv * 1024 + ln * 16;
  int LA0 = sinv(PA0), LA1 = sinv(PA0 + 8192), LB = sinv(PA0);
  const char* aS0 = (const char*)xf + (size_t)(brow + (LA0 >> 6)) * (H_ * 2) + (LA0 & 63);
  const char* aS1 = (const char*)xf + (size_t)(brow + (LA1 >> 6)) * (H_ * 2) + (LA1 & 63);
  const char* bS0 = (const char*)W1t + ((size_t)e * HH_ + bcol + (LB >> 6)) * (H_ * 2) + (LB & 63);

  f32x4 acc[4][4] = {};
  kloop<32, 5, 0, 0>(aS0, aS1, bS0, ldsc, aRd, bRd, wv, ln, acc, [](int) {});

  f16* C = he + (size_t)e * BS_ * HH_;
#pragma unroll
  for (int n = 0; n < 4; ++n) {
    int gc = bcol + wc * 64 + n * 16 + l15;
    float bias = b1[e * HH_ + gc];
#pragma unroll
    for (int m = 0; m < 4; ++m) {
      int gr0 = brow + wr * 64 + m * 16 + kq * 4;
#pragma unroll
      for (int r = 0; r < 4; ++r)
        C[(size_t)(gr0 + r) * HH_ + gc] = (f16)fmaxf(acc[m][n][r] + bias, 0.f);
    }
  }
}

// ------- GEMM2 fused over experts: out = sum_e w_e * tanh(he_e @ W2t_e^T + b2_e)
// grid 1024 = (nt 16) x (mt 64), block 512; continuous 128-tile pipeline
__global__ __launch_bounds__(512, 2) void gemm2_pipe(
    const f16* __restrict__ he, const f16* __restrict__ W2t,
    const float* __restrict__ b2, const float* __restrict__ wbuf,
    float* __restrict__ out) {
  __shared__ f16 lds[3 * 24576];
  char* ldsc = (char*)lds;
  int tid = threadIdx.x, wv = tid >> 6, ln = tid & 63, l15 = ln & 15, kq = ln >> 4;
  int wr = wv >> 1, wc = wv & 1;

  int id = blockIdx.x;
  int logical = (id & 7) * 128 + (id >> 3);
  int nt = logical & 15, mt = logical >> 4;
  int brow = mt * 256, bcol = nt * 128;
  int bb = brow >> 11;                      // batch index (2048 rows/batch)

  int mask = (ln & 7) << 4;
  int aRd = ((wr * 64 + l15) * 64 + kq * 16) ^ mask;
  int bRd = ((wc * 64 + l15) * 64 + kq * 16) ^ mask;

  int PA0 = wv * 1024 + ln * 16;
  int LA0 = sinv(PA0), LA1 = sinv(PA0 + 8192), LB = sinv(PA0);
  const char* aS0 = (const char*)he + (size_t)(brow + (LA0 >> 6)) * (HH_ * 2) + (LA0 & 63);
  const char* aS1 = (const char*)he + (size_t)(brow + (LA1 >> 6)) * (HH_ * 2) + (LA1 & 63);
  const char* bS0 = (const char*)W2t + (size_t)(bcol + (LB >> 6)) * (HH_ * 2) + (LB & 63);

  f32x4 acc[4][4] = {};
  f32x4 tot[4][4] = {};

  auto fold = [&](int e) {
    float we = wbuf[bb * E_ + e];
#pragma unroll
    for (int n = 0; n < 4; ++n) {
      float bias = b2[e * H_ + bcol + wc * 64 + n * 16 + l15];
#pragma unroll
      for (int m = 0; m < 4; ++m) {
#pragma unroll
        for (int r = 0; r < 4; ++r) {
          tot[m][n][r] += we * fast_tanh(acc[m][n][r] + bias);
          acc[m][n][r] = 0.f;
        }
      }
    }
  };

  // A expert stride: BS_*HH_*2 bytes = 1<<25 ; B: H_*HH_*2 = 1<<22
  kloop<128, 4, 25, 22>(aS0, aS1, bS0, ldsc, aRd, bRd, wv, ln, acc, fold);

#pragma unroll
  for (int n = 0; n < 4; ++n) {
    int gc = bcol + wc * 64 + n * 16 + l15;
#pragma unroll
    for (int m = 0; m < 4; ++m) {
      int gr0 = brow + wr * 64 + m * 16 + kq * 4;
#pragma unroll
      for (int r = 0; r < 4; ++r)
        out[(size_t)(gr0 + r) * H_ + gc] = tot[m][n][r];
    }
  }
}

// ------------------------------------------- x -> fp16 + pooled partials
__global__ void convert_x_pool(const float* __restrict__ x, f16* __restrict__ xf,
                               float* __restrict__ partial) {
  int h  = blockIdx.x * 256 + threadIdx.x;
  int sc = blockIdx.y;
  int b  = blockIdx.z;
  size_t base = ((size_t)b * S_ + sc * 64) * H_ + h;
  float sum = 0.f;
#pragma unroll 4
  for (int i = 0; i < 64; ++i) {
    float v = x[base + (size_t)i * H_];
    sum += v;
    xf[base + (size_t)i * H_] = (f16)v;
  }
  partial[((size_t)b * H_ + h) * 32 + sc] = sum;
}

__global__ void pool_finalize(const float* __restrict__ partial, float* __restrict__ pooled) {
  int i = blockIdx.x * 256 + threadIdx.x;
  float s = 0.f;
#pragma unroll
  for (int c = 0; c < 32; ++c) s += partial[(size_t)i * 32 + c];
  pooled[i] = s * (1.0f / S_);
}

// ----------------------------------------------------------- router (f32)
__global__ void router_kernel(const float* __restrict__ pooled,
                              const float* __restrict__ Wm1, const float* __restrict__ bm1,
                              const float* __restrict__ Wm2, const float* __restrict__ bm2,
                              const float* __restrict__ Wm3, const float* __restrict__ bm3,
                              const float* __restrict__ eff, float* __restrict__ wout) {
  __shared__ float pl[H_];
  __shared__ float h1[M_];
  __shared__ float h2[M_];
  __shared__ float lg[E_];
  int b = blockIdx.x;
  int t = threadIdx.x;

  for (int i = t; i < H_; i += 256) pl[i] = pooled[b * H_ + i];
  __syncthreads();

  float s = bm1[t];
  for (int k = 0; k < H_; ++k) s += pl[k] * Wm1[(size_t)k * M_ + t];
  h1[t] = fmaxf(s, 0.f);
  __syncthreads();

  s = bm2[t];
  for (int k = 0; k < M_; ++k) s += h1[k] * Wm2[k * M_ + t];
  h2[t] = fmaxf(s, 0.f);
  __syncthreads();

  if (t < E_) {
    float l = bm3[t];
    for (int k = 0; k < M_; ++k) l += h2[k] * Wm3[k * E_ + t];
    lg[t] = l;
  }
  __syncthreads();

  if (t == 0) {
    float p[E_], q[E_];
    float mx = -1e30f;
    for (int e = 0; e < E_; ++e) mx = fmaxf(mx, lg[e]);
    float den = 0.f;
    for (int e = 0; e < E_; ++e) { p[e] = __expf(lg[e] - mx); den += p[e]; }
    float inv = 1.f / den;
    for (int e = 0; e < E_; ++e) q[e] = p[e] * inv * eff[e];
    mx = -1e30f;
    for (int e = 0; e < E_; ++e) mx = fmaxf(mx, q[e]);
    den = 0.f;
    for (int e = 0; e < E_; ++e) { q[e] = __expf(q[e] - mx); den += q[e]; }
    inv = 1.f / den;
    for (int e = 0; e < E_; ++e) wout[b * E_ + e] = q[e] * inv;
  }
}

// ------------------------------------- weight transpose + f32->f16 convert
__global__ void transpose_cvt(const float* __restrict__ in, f16* __restrict__ out,
                              int R, int C) {
  __shared__ f16 tile[32][33];
  int e  = blockIdx.z;
  int c0 = blockIdx.x * 32, r0 = blockIdx.y * 32;
  int tx = threadIdx.x & 31, ty = threadIdx.x >> 5;
  const float* inp = in + (size_t)e * R * C;
  f16* outp = out + (size_t)e * R * C;
#pragma unroll
  for (int i = 0; i < 4; ++i) {
    int r = r0 + ty + i * 8;
    tile[ty + i * 8][tx] = (f16)inp[(size_t)r * C + c0 + tx];
  }
  __syncthreads();
#pragma unroll
  for (int i = 0; i < 4; ++i) {
    int c = c0 + ty + i * 8;
    outp[(size_t)c * R + r0 + tx] = tile[tx][ty + i * 8];
  }
}

// ---------------------------------------------------------------- launch
extern "C" void kernel_launch(void* const* d_in, const int* in_sizes, int n_in,
                              void* d_out, int out_size, void* d_ws, size_t ws_size,
                              hipStream_t stream) {
  const float* x   = (const float*)d_in[0];
  const float* Wm1 = (const float*)d_in[1];
  const float* bm1 = (const float*)d_in[2];
  const float* Wm2 = (const float*)d_in[3];
  const float* bm2 = (const float*)d_in[4];
  const float* Wm3 = (const float*)d_in[5];
  const float* bm3 = (const float*)d_in[6];
  const float* W1  = (const float*)d_in[7];
  const float* b1  = (const float*)d_in[8];
  const float* W2  = (const float*)d_in[9];
  const float* b2  = (const float*)d_in[10];
  const float* eff = (const float*)d_in[11];
  float* out = (float*)d_out;

  char* ws = (char*)d_ws;
  size_t off = 0;
  auto take = [&](size_t bytes) { void* p = ws + off; off += (bytes + 255) & ~(size_t)255; return p; };

  f16*   xf      = (f16*)  take((size_t)BS_ * H_ * 2);        // 64 MB
  f16*   W1t     = (f16*)  take((size_t)E_ * HH_ * H_ * 2);   // 32 MB
  f16*   W2t     = (f16*)  take((size_t)E_ * H_ * HH_ * 2);   // 32 MB
  float* partial = (float*)take((size_t)B_ * H_ * 32 * 4);    // 2 MB
  float* pooled  = (float*)take((size_t)B_ * H_ * 4);
  float* wbuf    = (float*)take(1024);
  f16*   he      = (f16*)  take((size_t)E_ * BS_ * HH_ * 2);  // 256 MB

  convert_x_pool<<<dim3(H_ / 256, S_ / 64, B_), 256, 0, stream>>>(x, xf, partial);
  pool_finalize<<<(B_ * H_) / 256, 256, 0, stream>>>(partial, pooled);
  router_kernel<<<B_, 256, 0, stream>>>(pooled, Wm1, bm1, Wm2, bm2, Wm3, bm3, eff, wbuf);
  transpose_cvt<<<dim3(HH_ / 32, H_ / 32, E_), 256, 0, stream>>>(W1, W1t, H_, HH_);
  transpose_cvt<<<dim3(H_ / 32, HH_ / 32, E_), 256, 0, stream>>>(W2, W2t, HH_, H_);

  gemm1_pipe<<<4096, 512, 0, stream>>>(xf, W1t, b1, he);
  gemm2_pipe<<<1024, 512, 0, stream>>>(he, W2t, b2, wbuf, out);
}

// Round 3
// 1482.711 us; speedup vs baseline: 1.2205x; 1.0943x over previous
//
#include <hip/hip_runtime.h>
#include <hip/hip_bf16.h>
#include <cstdint>
#include <cstddef>

#define B_   8
#define S_   2048
#define H_   2048
#define M_   256
#define E_   8
#define HH_  1024
#define BS_  (B_*S_)   // 16384

typedef _Float16 f16;
typedef _Float16 f16x8 __attribute__((ext_vector_type(8)));
typedef float    f32x4 __attribute__((ext_vector_type(4)));

// ---- pipelined-GEMM LDS geometry (bytes) ----
// slot = A[2 khalf][256 rows][32 f16] (32KB) + B[2 khalf][128 rows][32 f16] (16KB)
#define SLOT_B   49152
#define A_HALF_B 16384
#define B_OFF    32768
#define B_HALF_B 8192

__device__ __forceinline__ void gl_lds16(const void* g, void* l) {
  __builtin_amdgcn_global_load_lds(
      (const __attribute__((address_space(1))) uint32_t*)g,
      (__attribute__((address_space(3))) uint32_t*)l, 16, 0, 0);
}

// inverse of the LDS swizzle S(o) = o ^ (((o>>6)&7)<<4)   (GF(2)-linear, bijective)
__device__ __forceinline__ int sinv(int P) {
  int b8 = (P >> 8) & 1, b7 = (P >> 7) & 1, b6 = (P >> 6) & 1;
  return P ^ (b8 << 6) ^ (b7 << 5) ^ ((b6 ^ b8) << 4);
}

__device__ __forceinline__ float fast_tanh(float x) {
  x = fminf(fmaxf(x, -15.f), 15.f);
  float t = __expf(2.f * x);
  return (t - 1.f) / (t + 1.f);
}

// --------------------------------------------------------------------------
// Pipelined K-loop: 256x128 tile, 8 waves (4x2), wave tile 64x64, BK=64.
// 3 LDS slots; tile g computes from slot g%3 while staging tile g+2.
// Per tile: ONE barrier, ONE counted vmcnt; all 16 fragment ds_reads issued
// up front (register d-buf) so MFMA h0 hides the latency of h1's reads.
// --------------------------------------------------------------------------
template<int NG, int NT_LG, int ASEG_SH, int BSEG_SH, class F>
__device__ __forceinline__ void kloop(const char* aS0, const char* aS1,
    const char* bS0, char* ldsc, int aRd, int bRd, int wv, int ln,
    f32x4 (&acc)[4][4], F fold) {
  constexpr int NT = 1 << NT_LG;

  auto stage = [&](int gs, int ss, int h) {
    int tt = gs & (NT - 1);
    size_t ea = 0, eb = 0;
    if constexpr (ASEG_SH != 0) {
      int e = gs >> NT_LG;
      ea = (size_t)e << ASEG_SH;
      eb = (size_t)e << BSEG_SH;
    }
    int koff = tt * 128 + h * 64;
    char* dA = ldsc + ss * SLOT_B + h * A_HALF_B + wv * 1024 + ln * 16;
    gl_lds16(aS0 + ea + koff, dA);
    gl_lds16(aS1 + ea + koff, dA + 8192);
    char* dB = ldsc + ss * SLOT_B + B_OFF + h * B_HALF_B + wv * 1024 + ln * 16;
    gl_lds16(bS0 + eb + koff, dB);
  };

  // prologue: stage tiles 0,1 into slots 0,1; wait for tile 0 (oldest 6)
#pragma unroll
  for (int t = 0; t < 2; ++t) { stage(t, t, 0); stage(t, t, 1); }
  asm volatile("s_waitcnt vmcnt(6)" ::: "memory");
  __builtin_amdgcn_s_barrier();

  int s = 0;
#pragma unroll 1
  for (int g = 0; g < NG; ++g) {
    int ss = s + 2; if (ss >= 3) ss -= 3;
    const char* sbase = ldsc + s * SLOT_B;
    __builtin_amdgcn_sched_barrier(0);      // nothing hoists above tile start

    // all fragment reads for BOTH K-halves (slot fully resident at tile start)
    f16x8 af[2][4], bf[2][4];
#pragma unroll
    for (int h = 0; h < 2; ++h) {
      const char* aB = sbase + h * A_HALF_B + aRd;
      const char* bB = sbase + B_OFF + h * B_HALF_B + bRd;
#pragma unroll
      for (int m = 0; m < 4; ++m) af[h][m] = *(const f16x8*)(aB + m * 1024);
#pragma unroll
      for (int n = 0; n < 4; ++n) bf[h][n] = *(const f16x8*)(bB + n * 1024);
    }

    if ((g + 2) < NG) { stage(g + 2, ss, 0); stage(g + 2, ss, 1); }

    __builtin_amdgcn_s_setprio(1);
#pragma unroll
    for (int h = 0; h < 2; ++h)
#pragma unroll
      for (int m = 0; m < 4; ++m)
#pragma unroll
        for (int n = 0; n < 4; ++n)
          acc[m][n] = __builtin_amdgcn_mfma_f32_16x16x32_f16(af[h][m], bf[h][n], acc[m][n], 0, 0, 0);
    __builtin_amdgcn_s_setprio(0);

    if ((g & (NT - 1)) == (NT - 1)) fold(g >> NT_LG);

    __builtin_amdgcn_sched_barrier(0);      // nothing sinks below tile end
    if (g < NG - 2) { asm volatile("s_waitcnt vmcnt(6)" ::: "memory"); }
    else            { asm volatile("s_waitcnt vmcnt(0)" ::: "memory"); }
    __builtin_amdgcn_s_barrier();
    ++s; if (s >= 3) s -= 3;
  }
}

// ----------------- GEMM1: he[e] = relu(xf @ W1t[e]^T + b1[e]) --------------
// grid 4096 = (nt 8) x (mt 64) x (e 8), block 512
__global__ __launch_bounds__(512, 2) void gemm1_pipe(
    const f16* __restrict__ xf, const f16* __restrict__ W1t,
    const float* __restrict__ b1, f16* __restrict__ he) {
  __shared__ f16 lds[3 * 24576];
  char* ldsc = (char*)lds;
  int tid = threadIdx.x, wv = tid >> 6, ln = tid & 63, l15 = ln & 15, kq = ln >> 4;
  int wr = wv >> 1, wc = wv & 1;

  int id = blockIdx.x;
  int logical = (id & 7) * 512 + (id >> 3);      // XCD-contiguous chunks
  int nt = logical & 7, mt = (logical >> 3) & 63, e = logical >> 9;
  int brow = mt * 256, bcol = nt * 128;

  int mask = (ln & 7) << 4;
  int aRd = ((wr * 64 + l15) * 64 + kq * 16) ^ mask;
  int bRd = ((wc * 64 + l15) * 64 + kq * 16) ^ mask;

  int PA0 = wv * 1024 + ln * 16;
  int LA0 = sinv(PA0), LA1 = sinv(PA0 + 8192), LB = sinv(PA0);
  const char* aS0 = (const char*)xf + (size_t)(brow + (LA0 >> 6)) * (H_ * 2) + (LA0 & 63);
  const char* aS1 = (const char*)xf + (size_t)(brow + (LA1 >> 6)) * (H_ * 2) + (LA1 & 63);
  const char* bS0 = (const char*)W1t + ((size_t)e * HH_ + bcol + (LB >> 6)) * (H_ * 2) + (LB & 63);

  f32x4 acc[4][4] = {};
  kloop<32, 5, 0, 0>(aS0, aS1, bS0, ldsc, aRd, bRd, wv, ln, acc, [](int) {});

  f16* C = he + (size_t)e * BS_ * HH_;
#pragma unroll
  for (int n = 0; n < 4; ++n) {
    int gc = bcol + wc * 64 + n * 16 + l15;
    float bias = b1[e * HH_ + gc];
#pragma unroll
    for (int m = 0; m < 4; ++m) {
      int gr0 = brow + wr * 64 + m * 16 + kq * 4;
#pragma unroll
      for (int r = 0; r < 4; ++r)
        C[(size_t)(gr0 + r) * HH_ + gc] = (f16)fmaxf(acc[m][n][r] + bias, 0.f);
    }
  }
}

// ------- GEMM2 fused over experts: out = sum_e w_e * tanh(he_e @ W2t_e^T + b2_e)
// grid 1024 = (nt 16) x (mt 64), block 512; continuous 128-tile pipeline
__global__ __launch_bounds__(512, 2) void gemm2_pipe(
    const f16* __restrict__ he, const f16* __restrict__ W2t,
    const float* __restrict__ b2, const float* __restrict__ wbuf,
    float* __restrict__ out) {
  __shared__ f16 lds[3 * 24576];
  __shared__ float biasLDS[E_][128];   // this block's 128 cols, all experts
  __shared__ float wLDS[E_];
  char* ldsc = (char*)lds;
  int tid = threadIdx.x, wv = tid >> 6, ln = tid & 63, l15 = ln & 15, kq = ln >> 4;
  int wr = wv >> 1, wc = wv & 1;

  int id = blockIdx.x;
  int logical = (id & 7) * 128 + (id >> 3);
  int nt = logical & 15, mt = logical >> 4;
  int brow = mt * 256, bcol = nt * 128;
  int bb = brow >> 11;                      // batch index (2048 rows/batch)

  // preload bias/w into LDS so the K-loop has ZERO global VMEM ops
  {
    int i = tid;                            // 512 threads, 1024 floats
#pragma unroll
    for (int rep = 0; rep < 2; ++rep, i += 512) {
      int e = i >> 7, c = i & 127;
      biasLDS[e][c] = b2[e * H_ + bcol + c];
    }
    if (tid < E_) wLDS[tid] = wbuf[bb * E_ + tid];
  }
  __syncthreads();

  int mask = (ln & 7) << 4;
  int aRd = ((wr * 64 + l15) * 64 + kq * 16) ^ mask;
  int bRd = ((wc * 64 + l15) * 64 + kq * 16) ^ mask;

  int PA0 = wv * 1024 + ln * 16;
  int LA0 = sinv(PA0), LA1 = sinv(PA0 + 8192), LB = sinv(PA0);
  const char* aS0 = (const char*)he + (size_t)(brow + (LA0 >> 6)) * (HH_ * 2) + (LA0 & 63);
  const char* aS1 = (const char*)he + (size_t)(brow + (LA1 >> 6)) * (HH_ * 2) + (LA1 & 63);
  const char* bS0 = (const char*)W2t + (size_t)(bcol + (LB >> 6)) * (HH_ * 2) + (LB & 63);

  f32x4 acc[4][4] = {};
  f32x4 tot[4][4] = {};

  auto fold = [&](int e) {
    float we = wLDS[e];
#pragma unroll
    for (int n = 0; n < 4; ++n) {
      float bias = biasLDS[e][wc * 64 + n * 16 + l15];
#pragma unroll
      for (int m = 0; m < 4; ++m) {
#pragma unroll
        for (int r = 0; r < 4; ++r) {
          tot[m][n][r] += we * fast_tanh(acc[m][n][r] + bias);
          acc[m][n][r] = 0.f;
        }
      }
    }
  };

  // A expert stride: BS_*HH_*2 bytes = 1<<25 ; B: H_*HH_*2 = 1<<22
  kloop<128, 4, 25, 22>(aS0, aS1, bS0, ldsc, aRd, bRd, wv, ln, acc, fold);

#pragma unroll
  for (int n = 0; n < 4; ++n) {
    int gc = bcol + wc * 64 + n * 16 + l15;
#pragma unroll
    for (int m = 0; m < 4; ++m) {
      int gr0 = brow + wr * 64 + m * 16 + kq * 4;
#pragma unroll
      for (int r = 0; r < 4; ++r)
        out[(size_t)(gr0 + r) * H_ + gc] = tot[m][n][r];
    }
  }
}

// ------------------------------------------- x -> fp16 + pooled partials
__global__ void convert_x_pool(const float* __restrict__ x, f16* __restrict__ xf,
                               float* __restrict__ partial) {
  int h  = blockIdx.x * 256 + threadIdx.x;
  int sc = blockIdx.y;
  int b  = blockIdx.z;
  size_t base = ((size_t)b * S_ + sc * 64) * H_ + h;
  float sum = 0.f;
#pragma unroll 4
  for (int i = 0; i < 64; ++i) {
    float v = x[base + (size_t)i * H_];
    sum += v;
    xf[base + (size_t)i * H_] = (f16)v;
  }
  partial[((size_t)b * H_ + h) * 32 + sc] = sum;
}

__global__ void pool_finalize(const float* __restrict__ partial, float* __restrict__ pooled) {
  int i = blockIdx.x * 256 + threadIdx.x;
  float s = 0.f;
#pragma unroll
  for (int c = 0; c < 32; ++c) s += partial[(size_t)i * 32 + c];
  pooled[i] = s * (1.0f / S_);
}

// ----------------------------------------------------------- router (f32)
__global__ void router_kernel(const float* __restrict__ pooled,
                              const float* __restrict__ Wm1, const float* __restrict__ bm1,
                              const float* __restrict__ Wm2, const float* __restrict__ bm2,
                              const float* __restrict__ Wm3, const float* __restrict__ bm3,
                              const float* __restrict__ eff, float* __restrict__ wout) {
  __shared__ float pl[H_];
  __shared__ float h1[M_];
  __shared__ float h2[M_];
  __shared__ float lg[E_];
  int b = blockIdx.x;
  int t = threadIdx.x;

  for (int i = t; i < H_; i += 256) pl[i] = pooled[b * H_ + i];
  __syncthreads();

  float s = bm1[t];
  for (int k = 0; k < H_; ++k) s += pl[k] * Wm1[(size_t)k * M_ + t];
  h1[t] = fmaxf(s, 0.f);
  __syncthreads();

  s = bm2[t];
  for (int k = 0; k < M_; ++k) s += h1[k] * Wm2[k * M_ + t];
  h2[t] = fmaxf(s, 0.f);
  __syncthreads();

  if (t < E_) {
    float l = bm3[t];
    for (int k = 0; k < M_; ++k) l += h2[k] * Wm3[k * E_ + t];
    lg[t] = l;
  }
  __syncthreads();

  if (t == 0) {
    float p[E_], q[E_];
    float mx = -1e30f;
    for (int e = 0; e < E_; ++e) mx = fmaxf(mx, lg[e]);
    float den = 0.f;
    for (int e = 0; e < E_; ++e) { p[e] = __expf(lg[e] - mx); den += p[e]; }
    float inv = 1.f / den;
    for (int e = 0; e < E_; ++e) q[e] = p[e] * inv * eff[e];
    mx = -1e30f;
    for (int e = 0; e < E_; ++e) mx = fmaxf(mx, q[e]);
    den = 0.f;
    for (int e = 0; e < E_; ++e) { q[e] = __expf(q[e] - mx); den += q[e]; }
    inv = 1.f / den;
    for (int e = 0; e < E_; ++e) wout[b * E_ + e] = q[e] * inv;
  }
}

// ------------------------------------- weight transpose + f32->f16 convert
__global__ void transpose_cvt(const float* __restrict__ in, f16* __restrict__ out,
                              int R, int C) {
  __shared__ f16 tile[32][33];
  int e  = blockIdx.z;
  int c0 = blockIdx.x * 32, r0 = blockIdx.y * 32;
  int tx = threadIdx.x & 31, ty = threadIdx.x >> 5;
  const float* inp = in + (size_t)e * R * C;
  f16* outp = out + (size_t)e * R * C;
#pragma unroll
  for (int i = 0; i < 4; ++i) {
    int r = r0 + ty + i * 8;
    tile[ty + i * 8][tx] = (f16)inp[(size_t)r * C + c0 + tx];
  }
  __syncthreads();
#pragma unroll
  for (int i = 0; i < 4; ++i) {
    int c = c0 + ty + i * 8;
    outp[(size_t)c * R + r0 + tx] = tile[tx][ty + i * 8];
  }
}

// ---------------------------------------------------------------- launch
extern "C" void kernel_launch(void* const* d_in, const int* in_sizes, int n_in,
                              void* d_out, int out_size, void* d_ws, size_t ws_size,
                              hipStream_t stream) {
  const float* x   = (const float*)d_in[0];
  const float* Wm1 = (const float*)d_in[1];
  const float* bm1 = (const float*)d_in[2];
  const float* Wm2 = (const float*)d_in[3];
  const float* bm2 = (const float*)d_in[4];
  const float* Wm3 = (const float*)d_in[5];
  const float* bm3 = (const float*)d_in[6];
  const float* W1  = (const float*)d_in[7];
  const float* b1  = (const float*)d_in[8];
  const float* W2  = (const float*)d_in[9];
  const float* b2  = (const float*)d_in[10];
  const float* eff = (const float*)d_in[11];
  float* out = (float*)d_out;

  char* ws = (char*)d_ws;
  size_t off = 0;
  auto take = [&](size_t bytes) { void* p = ws + off; off += (bytes + 255) & ~(size_t)255; return p; };

  f16*   xf      = (f16*)  take((size_t)BS_ * H_ * 2);        // 64 MB
  f16*   W1t     = (f16*)  take((size_t)E_ * HH_ * H_ * 2);   // 32 MB
  f16*   W2t     = (f16*)  take((size_t)E_ * H_ * HH_ * 2);   // 32 MB
  float* partial = (float*)take((size_t)B_ * H_ * 32 * 4);    // 2 MB
  float* pooled  = (float*)take((size_t)B_ * H_ * 4);
  float* wbuf    = (float*)take(1024);
  f16*   he      = (f16*)  take((size_t)E_ * BS_ * HH_ * 2);  // 256 MB

  convert_x_pool<<<dim3(H_ / 256, S_ / 64, B_), 256, 0, stream>>>(x, xf, partial);
  pool_finalize<<<(B_ * H_) / 256, 256, 0, stream>>>(partial, pooled);
  router_kernel<<<B_, 256, 0, stream>>>(pooled, Wm1, bm1, Wm2, bm2, Wm3, bm3, eff, wbuf);
  transpose_cvt<<<dim3(HH_ / 32, H_ / 32, E_), 256, 0, stream>>>(W1, W1t, H_, HH_);
  transpose_cvt<<<dim3(H_ / 32, HH_ / 32, E_), 256, 0, stream>>>(W2, W2t, HH_, H_);

  gemm1_pipe<<<4096, 512, 0, stream>>>(xf, W1t, b1, he);
  gemm2_pipe<<<1024, 512, 0, stream>>>(he, W2t, b2, wbuf, out);
}

// Round 4
// 1412.174 us; speedup vs baseline: 1.2815x; 1.0499x over previous
//
#include <hip/hip_runtime.h>
#include <hip/hip_bf16.h>
#include <cstdint>
#include <cstddef>

#define B_   8
#define S_   2048
#define H_   2048
#define M_   256
#define E_   8
#define HH_  1024
#define BS_  (B_*S_)   // 16384

typedef _Float16 f16;
typedef _Float16 f16x8 __attribute__((ext_vector_type(8)));
typedef _Float16 f16x4 __attribute__((ext_vector_type(4)));
typedef float    f32x4 __attribute__((ext_vector_type(4)));

// half-slot = A[256 rows][32 k] (16KB) + B[256 rows][32 k] (16KB) = 32KB; ring of 4
#define HSLOT 32768

__device__ __forceinline__ void gl_lds16(const void* g, void* l) {
  __builtin_amdgcn_global_load_lds(
      (const __attribute__((address_space(1))) uint32_t*)g,
      (__attribute__((address_space(3))) uint32_t*)l, 16, 0, 0);
}

__device__ __forceinline__ float fast_tanh(float x) {
  x = fminf(fmaxf(x, -15.f), 15.f);
  float t = __expf(2.f * x);
  return (t - 1.f) / (t + 1.f);
}

// --------------------------------------------------------------------------
// 256x256 8-phase K-loop (template port): BK=64 as 2 halves of 32k.
// Waves 2M x 4N, wave tile 128x64 (acc[8][4] f32x4).
// LDS: 4 half-slots x 32KB ring. Swizzle: phys 16B slot = kq ^ ((row>>1)&3)
// (2-way max on fragment reads = free; staging keeps 64B-line coalescing).
// Per phase: {4-8 ds_read_b128, 2 gl_lds, barrier, lgkmcnt(0), 16 MFMA, barrier}.
// vmcnt(8) once per half (3 halves x 4 loads in flight). SEG: 8-expert K.
// --------------------------------------------------------------------------
template<int NG, bool SEG, int KB, class F>
__device__ __forceinline__ void kloop(const char* aBlk, const char* bBlk,
                                      char* ldsc, f32x4 (&acc)[8][4], F&& fold) {
  constexpr int NH = NG * 2;
  const int tid = threadIdx.x, ln = tid & 63, wv = tid >> 6;
  const int l15 = ln & 15, kq = ln >> 4;
  const int wm = wv >> 2, wn = wv & 3;

  // staging sources: piece j covers rows (tid>>2)+j*128; src pre-permuted (rule 21)
  const char* aPc[2]; const char* bPc[2];
#pragma unroll
  for (int j = 0; j < 2; ++j) {
    int row = (tid >> 2) + j * 128;
    int kqs = (tid & 3) ^ ((row >> 1) & 3);
    aPc[j] = aBlk + (size_t)row * KB + kqs * 16;
    bPc[j] = bBlk + (size_t)row * KB + kqs * 16;
  }
  const int rowA = wm * 128 + l15;
  const int rowB = wn * 64 + l15;
  const int aRd = rowA * 64 + ((kq ^ ((rowA >> 1) & 3)) << 4);
  const int bRd = 16384 + rowB * 64 + ((kq ^ ((rowB >> 1) & 3)) << 4);
  const int dst0 = tid * 16;

  auto stage2 = [&](int Ht, int op) {
    if (Ht >= NH) return;
    char* sb = ldsc + (Ht & 3) * HSLOT;
    size_t oa, ob;
    if constexpr (SEG) {
      size_t kb = (size_t)((Ht & 31) * 64);
      oa = ((size_t)(Ht >> 5) << 25) + kb;    // he expert stride 32MB
      ob = ((size_t)(Ht >> 5) << 22) + kb;    // W2t expert stride 4MB
    } else { oa = ob = (size_t)Ht * 64; }
    if (op == 0) {
      gl_lds16(aPc[0] + oa, sb + dst0);
      gl_lds16(aPc[1] + oa, sb + 8192 + dst0);
    } else {
      gl_lds16(bPc[0] + ob, sb + 16384 + dst0);
      gl_lds16(bPc[1] + ob, sb + 24576 + dst0);
    }
  };

  // prologue: halves 0..2 staged; wait half 0 (8 newer loads outstanding)
#pragma unroll
  for (int Ht = 0; Ht < 3; ++Ht) { stage2(Ht, 0); stage2(Ht, 1); }
  asm volatile("s_waitcnt vmcnt(8)" ::: "memory");
  __builtin_amdgcn_s_barrier();

#pragma unroll 1
  for (int g = 0; g < NG; ++g) {
#pragma unroll
    for (int kh = 0; kh < 2; ++kh) {
      const int H = g * 2 + kh;
      const char* sb = ldsc + (H & 3) * HSLOT;
      f16x8 bf[4];
#pragma unroll
      for (int mh = 0; mh < 2; ++mh) {
        f16x8 af[4];
        const char* ab = sb + aRd + mh * 4096;
#pragma unroll
        for (int m = 0; m < 4; ++m) af[m] = *(const f16x8*)(ab + m * 1024);
        if (mh == 0) {
          const char* bb = sb + bRd;
#pragma unroll
          for (int n = 0; n < 4; ++n) bf[n] = *(const f16x8*)(bb + n * 1024);
        }
        stage2(H + 3, mh);
        __builtin_amdgcn_s_barrier();
        asm volatile("s_waitcnt lgkmcnt(0)" ::: "memory");
        __builtin_amdgcn_sched_barrier(0);
        __builtin_amdgcn_s_setprio(1);
#pragma unroll
        for (int m = 0; m < 4; ++m)
#pragma unroll
          for (int n = 0; n < 4; ++n)
            acc[mh * 4 + m][n] = __builtin_amdgcn_mfma_f32_16x16x32_f16(
                af[m], bf[n], acc[mh * 4 + m][n], 0, 0, 0);
        __builtin_amdgcn_s_setprio(0);
        __builtin_amdgcn_sched_barrier(0);
        if (mh == 1) {   // once per half: ensure half H+1 resident for next phases
          if (H < NH - 3)       { asm volatile("s_waitcnt vmcnt(8)" ::: "memory"); }
          else if (H == NH - 3) { asm volatile("s_waitcnt vmcnt(4)" ::: "memory"); }
          else if (H == NH - 2) { asm volatile("s_waitcnt vmcnt(0)" ::: "memory"); }
        }
        __builtin_amdgcn_s_barrier();
      }
    }
    if constexpr (SEG) { if ((g & 15) == 15) fold(g >> 4); }
  }
}

// ----------------- GEMM1: he[e] = relu(xf @ W1t[e]^T + b1[e]) --------------
// grid 2048 = (nt 4) x (mt 64) x (e 8), block 512
__global__ __launch_bounds__(512, 2) void gemm1_t8(
    const f16* __restrict__ xf, const f16* __restrict__ W1t,
    const float* __restrict__ b1, f16* __restrict__ he) {
  __shared__ alignas(16) char ldsc[4 * HSLOT];
  int id = blockIdx.x;
  int logical = (id & 7) * 256 + (id >> 3);      // XCD-bijective (2048 % 8 == 0)
  int e = logical >> 8, mt = (logical >> 2) & 63, nt = logical & 3;
  int brow = mt * 256, bcol = nt * 256;

  const char* aBlk = (const char*)xf + (size_t)brow * 4096;
  const char* bBlk = (const char*)W1t + ((size_t)e << 22) + (size_t)bcol * 4096;

  f32x4 acc[8][4] = {};
  kloop<32, false, 4096>(aBlk, bBlk, ldsc, acc, [](int) {});

  const int tid = threadIdx.x, ln = tid & 63, wv = tid >> 6;
  const int l15 = ln & 15, kq4 = (ln >> 4) * 4;
  const int wm = wv >> 2, wn = wv & 3;
  f16* C = he + ((size_t)e << 24);               // BS*HH = 2^24 elems
#pragma unroll
  for (int n = 0; n < 4; ++n) {
    int gc = bcol + wn * 64 + n * 16 + l15;
    float bias = b1[e * HH_ + gc];
#pragma unroll
    for (int m = 0; m < 8; ++m) {
      int gr0 = brow + wm * 128 + m * 16 + kq4;
#pragma unroll
      for (int r = 0; r < 4; ++r)
        C[(size_t)(gr0 + r) * HH_ + gc] = (f16)fmaxf(acc[m][n][r] + bias, 0.f);
    }
  }
}

// ------- GEMM2 fused over experts: out = sum_e w_e * tanh(he_e @ W2t_e^T + b2_e)
// grid 512 = (nt 8) x (mt 64), block 512; K = 8 experts x 1024 continuous
__global__ __launch_bounds__(512, 2) void gemm2_t8(
    const f16* __restrict__ he, const f16* __restrict__ W2t,
    const float* __restrict__ b2, const float* __restrict__ wbuf,
    float* __restrict__ out) {
  __shared__ alignas(16) char ldsc[4 * HSLOT];
  __shared__ float biasLDS[E_][256];
  __shared__ float wLDS[E_];
  int id = blockIdx.x;
  int logical = (id & 7) * 64 + (id >> 3);       // XCD-bijective (512 % 8 == 0)
  int mt = logical >> 3, nt = logical & 7;
  int brow = mt * 256, bcol = nt * 256;
  int bb = brow >> 11;

  const int tid = threadIdx.x, ln = tid & 63, wv = tid >> 6;
  const int l15 = ln & 15, kq4 = (ln >> 4) * 4;
  const int wm = wv >> 2, wn = wv & 3;

  {
    int i = tid;
#pragma unroll
    for (int rep = 0; rep < 4; ++rep, i += 512)   // 8 experts x 256 cols
      biasLDS[i >> 8][i & 255] = b2[(size_t)(i >> 8) * H_ + bcol + (i & 255)];
    if (tid < E_) wLDS[tid] = wbuf[bb * E_ + tid];
  }
  __syncthreads();

  const char* aBlk = (const char*)he + (size_t)brow * 2048;
  const char* bBlk = (const char*)W2t + (size_t)bcol * 2048;

  f32x4 acc[8][4] = {};
  f16x4 tot[8][4] = {};                           // cross-expert accumulator (f16)

  auto fold = [&](int e) {
    float we = wLDS[e];
#pragma unroll
    for (int n = 0; n < 4; ++n) {
      float bias = biasLDS[e][wn * 64 + n * 16 + l15];
#pragma unroll
      for (int m = 0; m < 8; ++m) {
#pragma unroll
        for (int r = 0; r < 4; ++r) {
          tot[m][n][r] += (f16)(we * fast_tanh(acc[m][n][r] + bias));
          acc[m][n][r] = 0.f;
        }
      }
    }
  };

  kloop<128, true, 2048>(aBlk, bBlk, ldsc, acc, fold);

#pragma unroll
  for (int n = 0; n < 4; ++n) {
    int gc = bcol + wn * 64 + n * 16 + l15;
#pragma unroll
    for (int m = 0; m < 8; ++m) {
      int gr0 = brow + wm * 128 + m * 16 + kq4;
#pragma unroll
      for (int r = 0; r < 4; ++r)
        out[(size_t)(gr0 + r) * H_ + gc] = (float)tot[m][n][r];
    }
  }
}

// ------------------------------------------- x -> fp16 + pooled partials
__global__ void convert_x_pool(const float* __restrict__ x, f16* __restrict__ xf,
                               float* __restrict__ partial) {
  int h  = blockIdx.x * 256 + threadIdx.x;
  int sc = blockIdx.y;
  int b  = blockIdx.z;
  size_t base = ((size_t)b * S_ + sc * 64) * H_ + h;
  float sum = 0.f;
#pragma unroll 4
  for (int i = 0; i < 64; ++i) {
    float v = x[base + (size_t)i * H_];
    sum += v;
    xf[base + (size_t)i * H_] = (f16)v;
  }
  partial[((size_t)b * H_ + h) * 32 + sc] = sum;
}

__global__ void pool_finalize(const float* __restrict__ partial, float* __restrict__ pooled) {
  int i = blockIdx.x * 256 + threadIdx.x;
  float s = 0.f;
#pragma unroll
  for (int c = 0; c < 32; ++c) s += partial[(size_t)i * 32 + c];
  pooled[i] = s * (1.0f / S_);
}

// ----------------------------------------------------------- router (f32)
__global__ void router_kernel(const float* __restrict__ pooled,
                              const float* __restrict__ Wm1, const float* __restrict__ bm1,
                              const float* __restrict__ Wm2, const float* __restrict__ bm2,
                              const float* __restrict__ Wm3, const float* __restrict__ bm3,
                              const float* __restrict__ eff, float* __restrict__ wout) {
  __shared__ float pl[H_];
  __shared__ float h1[M_];
  __shared__ float h2[M_];
  __shared__ float lg[E_];
  int b = blockIdx.x;
  int t = threadIdx.x;

  for (int i = t; i < H_; i += 256) pl[i] = pooled[b * H_ + i];
  __syncthreads();

  float s = bm1[t];
  for (int k = 0; k < H_; ++k) s += pl[k] * Wm1[(size_t)k * M_ + t];
  h1[t] = fmaxf(s, 0.f);
  __syncthreads();

  s = bm2[t];
  for (int k = 0; k < M_; ++k) s += h1[k] * Wm2[k * M_ + t];
  h2[t] = fmaxf(s, 0.f);
  __syncthreads();

  if (t < E_) {
    float l = bm3[t];
    for (int k = 0; k < M_; ++k) l += h2[k] * Wm3[k * E_ + t];
    lg[t] = l;
  }
  __syncthreads();

  if (t == 0) {
    float p[E_], q[E_];
    float mx = -1e30f;
    for (int e = 0; e < E_; ++e) mx = fmaxf(mx, lg[e]);
    float den = 0.f;
    for (int e = 0; e < E_; ++e) { p[e] = __expf(lg[e] - mx); den += p[e]; }
    float inv = 1.f / den;
    for (int e = 0; e < E_; ++e) q[e] = p[e] * inv * eff[e];
    mx = -1e30f;
    for (int e = 0; e < E_; ++e) mx = fmaxf(mx, q[e]);
    den = 0.f;
    for (int e = 0; e < E_; ++e) { q[e] = __expf(q[e] - mx); den += q[e]; }
    inv = 1.f / den;
    for (int e = 0; e < E_; ++e) wout[b * E_ + e] = q[e] * inv;
  }
}

// ------------------------------------- weight transpose + f32->f16 convert
__global__ void transpose_cvt(const float* __restrict__ in, f16* __restrict__ out,
                              int R, int C) {
  __shared__ f16 tile[32][33];
  int e  = blockIdx.z;
  int c0 = blockIdx.x * 32, r0 = blockIdx.y * 32;
  int tx = threadIdx.x & 31, ty = threadIdx.x >> 5;
  const float* inp = in + (size_t)e * R * C;
  f16* outp = out + (size_t)e * R * C;
#pragma unroll
  for (int i = 0; i < 4; ++i) {
    int r = r0 + ty + i * 8;
    tile[ty + i * 8][tx] = (f16)inp[(size_t)r * C + c0 + tx];
  }
  __syncthreads();
#pragma unroll
  for (int i = 0; i < 4; ++i) {
    int c = c0 + ty + i * 8;
    outp[(size_t)c * R + r0 + tx] = tile[tx][ty + i * 8];
  }
}

// ---------------------------------------------------------------- launch
extern "C" void kernel_launch(void* const* d_in, const int* in_sizes, int n_in,
                              void* d_out, int out_size, void* d_ws, size_t ws_size,
                              hipStream_t stream) {
  const float* x   = (const float*)d_in[0];
  const float* Wm1 = (const float*)d_in[1];
  const float* bm1 = (const float*)d_in[2];
  const float* Wm2 = (const float*)d_in[3];
  const float* bm2 = (const float*)d_in[4];
  const float* Wm3 = (const float*)d_in[5];
  const float* bm3 = (const float*)d_in[6];
  const float* W1  = (const float*)d_in[7];
  const float* b1  = (const float*)d_in[8];
  const float* W2  = (const float*)d_in[9];
  const float* b2  = (const float*)d_in[10];
  const float* eff = (const float*)d_in[11];
  float* out = (float*)d_out;

  char* ws = (char*)d_ws;
  size_t off = 0;
  auto take = [&](size_t bytes) { void* p = ws + off; off += (bytes + 255) & ~(size_t)255; return p; };

  f16*   xf      = (f16*)  take((size_t)BS_ * H_ * 2);        // 64 MB
  f16*   W1t     = (f16*)  take((size_t)E_ * HH_ * H_ * 2);   // 32 MB
  f16*   W2t     = (f16*)  take((size_t)E_ * H_ * HH_ * 2);   // 32 MB
  float* partial = (float*)take((size_t)B_ * H_ * 32 * 4);    // 2 MB
  float* pooled  = (float*)take((size_t)B_ * H_ * 4);
  float* wbuf    = (float*)take(1024);
  f16*   he      = (f16*)  take((size_t)E_ * BS_ * HH_ * 2);  // 256 MB

  convert_x_pool<<<dim3(H_ / 256, S_ / 64, B_), 256, 0, stream>>>(x, xf, partial);
  pool_finalize<<<(B_ * H_) / 256, 256, 0, stream>>>(partial, pooled);
  router_kernel<<<B_, 256, 0, stream>>>(pooled, Wm1, bm1, Wm2, bm2, Wm3, bm3, eff, wbuf);
  transpose_cvt<<<dim3(HH_ / 32, H_ / 32, E_), 256, 0, stream>>>(W1, W1t, H_, HH_);
  transpose_cvt<<<dim3(H_ / 32, HH_ / 32, E_), 256, 0, stream>>>(W2, W2t, HH_, H_);

  gemm1_t8<<<2048, 512, 0, stream>>>(xf, W1t, b1, he);
  gemm2_t8<<<512, 512, 0, stream>>>(he, W2t, b2, wbuf, out);
}